// Round 14
// baseline (4371.680 us; speedup 1.0000x reference)
//
#include <hip/hip_runtime.h>
#include <stdint.h>

typedef unsigned short u16;
typedef __bf16 bf16x8 __attribute__((ext_vector_type(8)));
typedef float  f32x4  __attribute__((ext_vector_type(4)));

#define GPTR(p) ((const __attribute__((address_space(1))) void*)(p))
#define LPTR(p) ((__attribute__((address_space(3))) void*)(p))

__device__ __forceinline__ u16 f2bf(float f) {
  uint32_t u = __float_as_uint(f);
  u += 0x7FFFu + ((u >> 16) & 1u);
  return (u16)(u >> 16);
}
__device__ __forceinline__ float bf2f(u16 h) {
  return __uint_as_float(((uint32_t)h) << 16);
}
__device__ __forceinline__ float sigf(float x) { return 1.0f / (1.0f + __expf(-x)); }
__device__ __forceinline__ float tanhf_(float x) { return 1.0f - 2.0f / (__expf(2.0f * x) + 1.0f); }

// ---------------- embedding gather ----------------
__global__ void k_emb(const int* __restrict__ seq, const float* __restrict__ wemb,
                      u16* __restrict__ x1) {
  const int row = blockIdx.x;          // 0..16383
  const int tok = seq[row];
  float4 v = ((const float4*)(wemb + (size_t)tok * 1024))[threadIdx.x];
  uint32_t lo = (uint32_t)f2bf(v.x) | ((uint32_t)f2bf(v.y) << 16);
  uint32_t hi = (uint32_t)f2bf(v.z) | ((uint32_t)f2bf(v.w) << 16);
  *(uint2*)(x1 + (size_t)row * 1024 + threadIdx.x * 4) = make_uint2(lo, hi);
}

// ---------------- marker index per row ----------------
__global__ void k_idx(const int* __restrict__ seq, int* __restrict__ idxb) {
  const int tid = threadIdx.x;         // 256
  const int b = tid >> 3, part = tid & 7;
  for (int t = part * 64; t < part * 64 + 64; ++t)
    if (seq[b * 512 + t] == 50000) idxb[b] = t;
}

// ---------------- cast 4096x1024 f32 -> bf16 ----------------
__global__ void k_cast(const float* __restrict__ src, u16* __restrict__ dst) {
  const int i = blockIdx.x * 256 + threadIdx.x;
  float4 v = ((const float4*)src)[i];
  uint32_t lo = (uint32_t)f2bf(v.x) | ((uint32_t)f2bf(v.y) << 16);
  uint32_t hi = (uint32_t)f2bf(v.z) | ((uint32_t)f2bf(v.w) << 16);
  *(uint2*)(dst + (size_t)i * 4) = make_uint2(lo, hi);
}

// ---------------- GEMM: gx[d][t][b][(j>>4)*64 + q*16 + (j&15)] ----------------
__global__ __launch_bounds__(256) void k_gemm(
    const u16* __restrict__ X, const u16* __restrict__ W,
    const float* __restrict__ bias, u16* __restrict__ gx)
{
  __shared__ u16 As[128][32];
  __shared__ u16 Bs[128][32];
  const int tid = threadIdx.x;
  const int lane = tid & 63;
  const int wv = tid >> 6;
  const int wm = wv >> 1, wn = wv & 1;
  const int bm = blockIdx.x, bn = blockIdx.y;
  const int srow = tid >> 2;
  const int scg = (tid & 3) * 8;
  const u16* Xb = X + (size_t)bm * 128 * 1024;
  const u16* Wb = W + (size_t)bn * 128 * 1024;
  f32x4 acc[4][4] = {};
  for (int k0 = 0; k0 < 1024; k0 += 32) {
    __builtin_amdgcn_global_load_lds(GPTR(Xb + (size_t)srow * 1024 + k0 + scg),        LPTR(&As[srow][scg]),       16, 0, 0);
    __builtin_amdgcn_global_load_lds(GPTR(Xb + (size_t)(srow + 64) * 1024 + k0 + scg), LPTR(&As[srow + 64][scg]), 16, 0, 0);
    __builtin_amdgcn_global_load_lds(GPTR(Wb + (size_t)srow * 1024 + k0 + scg),        LPTR(&Bs[srow][scg]),       16, 0, 0);
    __builtin_amdgcn_global_load_lds(GPTR(Wb + (size_t)(srow + 64) * 1024 + k0 + scg), LPTR(&Bs[srow + 64][scg]), 16, 0, 0);
    __syncthreads();
    const int kg = (lane >> 4) * 8;
    bf16x8 a4[4], b4[4];
    #pragma unroll
    for (int mt = 0; mt < 4; ++mt) a4[mt] = *(const bf16x8*)&As[wm * 64 + mt * 16 + (lane & 15)][kg];
    #pragma unroll
    for (int nt = 0; nt < 4; ++nt) b4[nt] = *(const bf16x8*)&Bs[wn * 64 + nt * 16 + (lane & 15)][kg];
    #pragma unroll
    for (int mt = 0; mt < 4; ++mt)
      #pragma unroll
      for (int nt = 0; nt < 4; ++nt)
        acc[mt][nt] = __builtin_amdgcn_mfma_f32_16x16x32_bf16(a4[mt], b4[nt], acc[mt][nt], 0, 0, 0);
    __syncthreads();
  }
  #pragma unroll
  for (int mt = 0; mt < 4; ++mt) {
    const int mbase = bm * 128 + wm * 64 + mt * 16 + ((lane >> 4) << 2);
    #pragma unroll
    for (int nt = 0; nt < 4; ++nt) {
      const int n = bn * 128 + wn * 64 + nt * 16 + (lane & 15);
      const float bi = bias[n];
      const int d = n >> 11;
      const int nn = n & 2047;
      const int q = nn >> 9;          // gate
      const int j = nn & 511;         // h column
      const int col = (j >> 4) * 64 + q * 16 + (j & 15);
      #pragma unroll
      for (int r = 0; r < 4; ++r) {
        const int mm = mbase + r;
        const int b = mm >> 9, t = mm & 511;
        gx[((size_t)(d * 512 + t) * 32 + b) * 2048 + col] = f2bf(acc[mt][nt][r] + bi);
      }
    }
  }
}

// ---------------- persistent bidirectional recurrence (sleep + speculative staged bulk) ----------------
// 64 blocks: dir = bid>>5, db = bid&31 owns h-cols [db*16, db*16+16).
// hstep layout: [dir][slot s][producer db][row 0..31][16 cols] bf16 — producer stores
// ONE CONTIGUOUS 1KB chunk per step; consumer wave loads 2KB-strided 512B windows.
// Slots pre-memset 0xFF (|h|<1 so a valid pair is never 0xFFFFFFFF).
// Protocol (single variable vs round 13: probe spin DELETED): s_sleep(16) pre-pays the
// store-visibility window, then the 16 bulk loads are issued speculatively and staged
// vmcnt(8)/vmcnt(0) under the MFMA chain; masked sentinel backstop rounds do detection
// (common case: round 1 already valid). Terminating by construction.
__global__ __launch_bounds__(256, 1) void k_rec(
    const u16* __restrict__ gx, const float* __restrict__ whh,
    u16* __restrict__ xout, u16* hstep)
{
  const int bid = blockIdx.x;
  const int dir = bid >> 5;
  const int db = bid & 31;
  const int j0 = db * 16;
  const int tid = threadIdx.x;
  const int lane = tid & 63;
  const int wv = tid >> 6;
  const int mh = wv >> 1, nh = wv & 1;
  const int R = lane & 15;
  const int ks = lane >> 4;

  __shared__ float G[2][32][68];

  // ---- Whh chunk -> registers (bf16 B-fragments)
  bf16x8 bw[2][16];
  {
    #pragma unroll
    for (int nt = 0; nt < 2; ++nt) {
      const int q = nh * 2 + nt;   // gate: 0=i 1=f 2=g 3=o
      const float* wp = whh + ((size_t)dir * 2048 + q * 512 + j0 + R) * 512 + ks * 8;
      #pragma unroll
      for (int kt = 0; kt < 16; ++kt) {
        float4 v0 = *(const float4*)(wp + kt * 32);
        float4 v1 = *(const float4*)(wp + kt * 32 + 4);
        union { u16 u[8]; bf16x8 v; } t;
        t.u[0] = f2bf(v0.x); t.u[1] = f2bf(v0.y); t.u[2] = f2bf(v0.z); t.u[3] = f2bf(v0.w);
        t.u[4] = f2bf(v1.x); t.u[5] = f2bf(v1.y); t.u[6] = f2bf(v1.z); t.u[7] = f2bf(v1.w);
        bw[nt][kt] = t.v;
      }
    }
  }

  const int eb = tid >> 3;          // batch row for elementwise
  const int pr = (tid & 7) * 2;     // h-col pair within chunk
  float c0 = 0.f, c1 = 0.f;

  const size_t dirbase = (size_t)dir * 512 * 16384;
  // A-frag (kt): producer p = 2*kt + (ks>>1); addr = dirbase + slot + p*512 + row*16 + (ks&1)*8
  const u16* apbase = hstep + dirbase + (size_t)(ks >> 1) * 512 + (mh * 16 + R) * 16 + (ks & 1) * 8;
  const u16* gxeb   = gx + ((size_t)dir * 512 * 32 + eb) * 2048 + db * 64 + pr;

  uint32_t gq[4];
  {
    const int t0 = dir ? 511 : 0;
    const uint32_t* g0 = (const uint32_t*)(gxeb + (size_t)t0 * 65536);
    gq[0] = g0[0]; gq[1] = g0[8]; gq[2] = g0[16]; gq[3] = g0[24];
  }

  for (int s = 0; s < 512; ++s) {
    const int tcur = dir ? (511 - s) : s;
    const int gb = s & 1;
    f32x4 acc0 = {0.f,0.f,0.f,0.f}, acc1 = {0.f,0.f,0.f,0.f};

    if (s) {
      const size_t slot = (size_t)(s - 1) * 16384;
      const u16* ap = apbase + slot;
      // ---- sleep pre-pays the store-visibility window (validated neutral-or-better r13)
      __builtin_amdgcn_s_sleep(16);
      // ---- speculative bulk A-fragment loads (16 x dwordx4, 2KB stride) — no probe
      uint4 afu[16];
      #pragma unroll
      for (int kt = 0; kt < 16; ++kt)
        asm volatile("global_load_dwordx4 %0, %1, off sc0 sc1"
                     : "=v"(afu[kt]) : "v"(ap + kt * 1024) : "memory");
      // ---- stage 1: wait until only 8 newest outstanding (drains stores+gx+frags 0..7)
      asm volatile("s_waitcnt vmcnt(8)" ::: "memory");
      __builtin_amdgcn_sched_barrier(0);
      while (true) {   // detection backstop, frags 0..7 (common case: passes round 1)
        unsigned mask = 0;
        #pragma unroll
        for (int kt = 0; kt < 8; ++kt) {
          int ok = (afu[kt].x != 0xFFFFFFFFu) && (afu[kt].y != 0xFFFFFFFFu) &&
                   (afu[kt].z != 0xFFFFFFFFu) && (afu[kt].w != 0xFFFFFFFFu);
          if (!__all(ok)) mask |= 1u << kt;
        }
        if (!mask) break;
        #pragma unroll
        for (int kt = 0; kt < 8; ++kt)
          if (mask & (1u << kt))
            asm volatile("global_load_dwordx4 %0, %1, off sc0 sc1"
                         : "=v"(afu[kt]) : "v"(ap + kt * 1024) : "memory");
        asm volatile("s_waitcnt vmcnt(0)" ::: "memory");
        __builtin_amdgcn_sched_barrier(0);
      }
      f32x4 a0 = {0.f,0.f,0.f,0.f}, a1 = {0.f,0.f,0.f,0.f};
      f32x4 b0 = {0.f,0.f,0.f,0.f}, b1 = {0.f,0.f,0.f,0.f};
      #pragma unroll
      for (int kt = 0; kt < 8; kt += 2) {
        bf16x8 x = __builtin_bit_cast(bf16x8, afu[kt]);
        bf16x8 y = __builtin_bit_cast(bf16x8, afu[kt + 1]);
        a0 = __builtin_amdgcn_mfma_f32_16x16x32_bf16(x, bw[0][kt],     a0, 0, 0, 0);
        a1 = __builtin_amdgcn_mfma_f32_16x16x32_bf16(x, bw[1][kt],     a1, 0, 0, 0);
        b0 = __builtin_amdgcn_mfma_f32_16x16x32_bf16(y, bw[0][kt + 1], b0, 0, 0, 0);
        b1 = __builtin_amdgcn_mfma_f32_16x16x32_bf16(y, bw[1][kt + 1], b1, 0, 0, 0);
      }
      // ---- stage 2: frags 8..15
      asm volatile("s_waitcnt vmcnt(0)" ::: "memory");
      __builtin_amdgcn_sched_barrier(0);
      while (true) {   // detection backstop, frags 8..15
        unsigned mask = 0;
        #pragma unroll
        for (int kt = 8; kt < 16; ++kt) {
          int ok = (afu[kt].x != 0xFFFFFFFFu) && (afu[kt].y != 0xFFFFFFFFu) &&
                   (afu[kt].z != 0xFFFFFFFFu) && (afu[kt].w != 0xFFFFFFFFu);
          if (!__all(ok)) mask |= 1u << (kt - 8);
        }
        if (!mask) break;
        #pragma unroll
        for (int kt = 8; kt < 16; ++kt)
          if (mask & (1u << (kt - 8)))
            asm volatile("global_load_dwordx4 %0, %1, off sc0 sc1"
                         : "=v"(afu[kt]) : "v"(ap + kt * 1024) : "memory");
        asm volatile("s_waitcnt vmcnt(0)" ::: "memory");
        __builtin_amdgcn_sched_barrier(0);
      }
      #pragma unroll
      for (int kt = 8; kt < 16; kt += 2) {
        bf16x8 x = __builtin_bit_cast(bf16x8, afu[kt]);
        bf16x8 y = __builtin_bit_cast(bf16x8, afu[kt + 1]);
        a0 = __builtin_amdgcn_mfma_f32_16x16x32_bf16(x, bw[0][kt],     a0, 0, 0, 0);
        a1 = __builtin_amdgcn_mfma_f32_16x16x32_bf16(x, bw[1][kt],     a1, 0, 0, 0);
        b0 = __builtin_amdgcn_mfma_f32_16x16x32_bf16(y, bw[0][kt + 1], b0, 0, 0, 0);
        b1 = __builtin_amdgcn_mfma_f32_16x16x32_bf16(y, bw[1][kt + 1], b1, 0, 0, 0);
      }
      acc0 = a0 + b0;
      acc1 = a1 + b1;
    }

    #pragma unroll
    for (int r = 0; r < 4; ++r) {
      G[gb][mh * 16 + (lane >> 4) * 4 + r][nh * 32 + (lane & 15)]      = acc0[r];
      G[gb][mh * 16 + (lane >> 4) * 4 + r][nh * 32 + 16 + (lane & 15)] = acc1[r];
    }
    __syncthreads();                                   // G[gb] complete

    // ---- elementwise LSTM cell for (eb, j0+pr) and (eb, j0+pr+1)
    {
      float i0 = G[gb][eb][pr]      + bf2f((u16)(gq[0] & 0xFFFF));
      float i1 = G[gb][eb][pr + 1]  + bf2f((u16)(gq[0] >> 16));
      float f0 = G[gb][eb][pr + 16] + bf2f((u16)(gq[1] & 0xFFFF));
      float f1 = G[gb][eb][pr + 17] + bf2f((u16)(gq[1] >> 16));
      float g0 = G[gb][eb][pr + 32] + bf2f((u16)(gq[2] & 0xFFFF));
      float g1 = G[gb][eb][pr + 33] + bf2f((u16)(gq[2] >> 16));
      float o0 = G[gb][eb][pr + 48] + bf2f((u16)(gq[3] & 0xFFFF));
      float o1 = G[gb][eb][pr + 49] + bf2f((u16)(gq[3] >> 16));
      c0 = sigf(f0) * c0 + sigf(i0) * tanhf_(g0);
      c1 = sigf(f1) * c1 + sigf(i1) * tanhf_(g1);
      float h0 = sigf(o0) * tanhf_(c0);
      float h1 = sigf(o1) * tanhf_(c1);
      uint32_t hp = (uint32_t)f2bf(h0) | ((uint32_t)f2bf(h1) << 16);
      // contiguous 1KB producer chunk: [slot s][db][eb][pr]
      u16* hdst = hstep + dirbase + (size_t)s * 16384 + (size_t)db * 512 + eb * 16 + pr;
      asm volatile("global_store_dword %0, %1, off sc0 sc1"
                   :: "v"(hdst), "v"(hp) : "memory");
      *(uint32_t*)(xout + ((size_t)eb * 512 + tcur) * 1024 + dir * 512 + j0 + pr) = hp;
    }
    // ---- software-pipelined gx for next step (plain loads; drained by next stage-1 wait)
    if (s < 511) {
      const int tn = dir ? (511 - (s + 1)) : (s + 1);
      const uint32_t* gn = (const uint32_t*)(gxeb + (size_t)tn * 65536);
      gq[0] = gn[0]; gq[1] = gn[8]; gq[2] = gn[16]; gq[3] = gn[24];
    }
    // no trailing barrier: G ping-pong, next step writes G[gb^1]
  }
}

// ---------------- classifier stage 1 ----------------
__global__ void k_cls1(const u16* __restrict__ x3, const int* __restrict__ idxb,
                       const float* __restrict__ w1, const float* __restrict__ b1,
                       float* __restrict__ h1) {
  __shared__ u16 hid[32][1024];
  const int tid = threadIdx.x;
  for (int g = tid; g < 4096; g += 256) {
    const int b = g >> 7;
    const int c8 = (g & 127) * 8;
    *(uint4*)&hid[b][c8] = *(const uint4*)(x3 + ((size_t)b * 512 + idxb[b]) * 1024 + c8);
  }
  __syncthreads();
  for (int p = tid; p < 1024; p += 256) {
    const int j = blockIdx.x * 32 + (p >> 5);
    const int b = p & 31;
    const float4* wr = (const float4*)(w1 + (size_t)j * 1024);
    float s = 0.f;
    for (int k4 = 0; k4 < 256; ++k4) {
      float4 wv = wr[k4];
      const int k = k4 * 4;
      s += bf2f(hid[b][k]) * wv.x + bf2f(hid[b][k + 1]) * wv.y
         + bf2f(hid[b][k + 2]) * wv.z + bf2f(hid[b][k + 3]) * wv.w;
    }
    h1[b * 512 + j] = tanhf_(s + b1[j]);
  }
}

// ---------------- classifier stage 2: BCE-with-logits mean ----------------
__global__ void k_cls2(const float* __restrict__ h1, const float* __restrict__ w2,
                       const float* __restrict__ b2, const float* __restrict__ label,
                       float* __restrict__ out) {
  const int lane = threadIdx.x;   // 64
  float loss = 0.f;
  for (int b = 0; b < 32; ++b) {
    float s = 0.f;
    for (int k = lane; k < 512; k += 64) s += h1[b * 512 + k] * w2[k];
    for (int off = 32; off; off >>= 1) s += __shfl_down(s, off);
    if (lane == 0) {
      const float z = s + b2[0];
      const float y = label[b];
      const float sp = fmaxf(z, 0.f) + log1pf(__expf(-fabsf(z)));
      loss += sp - z * y;
    }
  }
  if (lane == 0) out[0] = loss / 32.0f;
}

extern "C" void kernel_launch(void* const* d_in, const int* in_sizes, int n_in,
                              void* d_out, int out_size, void* d_ws, size_t ws_size,
                              hipStream_t stream) {
  const int*   seq   = (const int*)  d_in[0];
  const float* label = (const float*)d_in[1];
  const float* wemb  = (const float*)d_in[2];
  const float* wih   = (const float*)d_in[3];
  const float* whh   = (const float*)d_in[4];
  const float* bb    = (const float*)d_in[5];
  const float* w1    = (const float*)d_in[6];
  const float* b1    = (const float*)d_in[7];
  const float* w2    = (const float*)d_in[8];
  const float* b2    = (const float*)d_in[9];

  u16* x1   = (u16*)d_ws;                       // [32][512][1024] bf16 (hstep region for layer1)
  u16* x2   = x1 + (size_t)16777216;            // [32][512][1024] bf16 (hstep region for layer2)
  u16* gxb  = x2 + (size_t)16777216;            // [2][512][32][2048] bf16
  u16* wb   = gxb + (size_t)67108864;           // [4096][1024] bf16
  float* h1 = (float*)(wb + 4194304);           // [32][512] f32
  int* idxb = (int*)(h1 + 16384);               // [32]

  // layer 1
  k_emb<<<16384, 256, 0, stream>>>(seq, wemb, x1);
  k_idx<<<1, 256, 0, stream>>>(seq, idxb);
  k_cast<<<4096, 256, 0, stream>>>(wih, wb);
  k_gemm<<<dim3(128, 32), 256, 0, stream>>>(x1, wb, bb, gxb);
  hipMemsetAsync(x1, 0xFF, (size_t)33554432, stream);      // hstep sentinel (layer1)
  k_rec<<<64, 256, 0, stream>>>(gxb, whh, x2, x1);
  // layer 2
  k_cast<<<4096, 256, 0, stream>>>(wih + 4194304, wb);
  k_gemm<<<dim3(128, 32), 256, 0, stream>>>(x2, wb, bb + 4096, gxb);
  hipMemsetAsync(x2, 0xFF, (size_t)33554432, stream);      // hstep sentinel (layer2)
  k_rec<<<64, 256, 0, stream>>>(gxb, whh + 2097152, x1, x2);
  // head
  k_cls1<<<16, 256, 0, stream>>>(x1, idxb, w1, b1, h1);
  k_cls2<<<1, 64, 0, stream>>>(h1, w2, b2, label, (float*)d_out);
}

// Round 15
// 3999.593 us; speedup vs baseline: 1.0930x; 1.0930x over previous
//
#include <hip/hip_runtime.h>
#include <stdint.h>

typedef unsigned short u16;
typedef __bf16 bf16x8 __attribute__((ext_vector_type(8)));
typedef float  f32x4  __attribute__((ext_vector_type(4)));

#define GPTR(p) ((const __attribute__((address_space(1))) void*)(p))
#define LPTR(p) ((__attribute__((address_space(3))) void*)(p))

__device__ __forceinline__ u16 f2bf(float f) {
  uint32_t u = __float_as_uint(f);
  u += 0x7FFFu + ((u >> 16) & 1u);
  return (u16)(u >> 16);
}
__device__ __forceinline__ float bf2f(u16 h) {
  return __uint_as_float(((uint32_t)h) << 16);
}
__device__ __forceinline__ float sigf(float x) { return 1.0f / (1.0f + __expf(-x)); }
__device__ __forceinline__ float tanhf_(float x) { return 1.0f - 2.0f / (__expf(2.0f * x) + 1.0f); }

// ---------------- embedding gather ----------------
__global__ void k_emb(const int* __restrict__ seq, const float* __restrict__ wemb,
                      u16* __restrict__ x1) {
  const int row = blockIdx.x;          // 0..16383
  const int tok = seq[row];
  float4 v = ((const float4*)(wemb + (size_t)tok * 1024))[threadIdx.x];
  uint32_t lo = (uint32_t)f2bf(v.x) | ((uint32_t)f2bf(v.y) << 16);
  uint32_t hi = (uint32_t)f2bf(v.z) | ((uint32_t)f2bf(v.w) << 16);
  *(uint2*)(x1 + (size_t)row * 1024 + threadIdx.x * 4) = make_uint2(lo, hi);
}

// ---------------- marker index per row ----------------
__global__ void k_idx(const int* __restrict__ seq, int* __restrict__ idxb) {
  const int tid = threadIdx.x;         // 256
  const int b = tid >> 3, part = tid & 7;
  for (int t = part * 64; t < part * 64 + 64; ++t)
    if (seq[b * 512 + t] == 50000) idxb[b] = t;
}

// ---------------- cast 4096x1024 f32 -> bf16 ----------------
__global__ void k_cast(const float* __restrict__ src, u16* __restrict__ dst) {
  const int i = blockIdx.x * 256 + threadIdx.x;
  float4 v = ((const float4*)src)[i];
  uint32_t lo = (uint32_t)f2bf(v.x) | ((uint32_t)f2bf(v.y) << 16);
  uint32_t hi = (uint32_t)f2bf(v.z) | ((uint32_t)f2bf(v.w) << 16);
  *(uint2*)(dst + (size_t)i * 4) = make_uint2(lo, hi);
}

// ---------------- GEMM: BK=64 + st-swizzle; gx[d][t][b][(j>>4)*64 + q*16 + (j&15)] ----------------
// LDS tiles [128][64] u16 (128B rows = exact 32-bank stride): conflict fixed via
// both-sides XOR swizzle (m201/m173): linear LDS dest for global_load_lds, INVERSE-
// swizzled global source colgroup (lane&7)^(lane>>3), XOR'd ds_read index (kq^(row&7))*8.
__global__ __launch_bounds__(256) void k_gemm(
    const u16* __restrict__ X, const u16* __restrict__ W,
    const float* __restrict__ bias, u16* __restrict__ gx)
{
  __shared__ u16 As[128 * 64];   // 16 KB
  __shared__ u16 Bs[128 * 64];   // 16 KB
  const int tid = threadIdx.x;
  const int lane = tid & 63;
  const int wv = tid >> 6;
  const int wm = wv >> 1, wn = wv & 1;
  const int bm = blockIdx.x, bn = blockIdx.y;
  const u16* Xb = X + (size_t)bm * 128 * 1024;
  const u16* Wb = W + (size_t)bn * 128 * 1024;
  // staging geometry: chunk c covers rows c*8..c*8+7; lane i stages row c*8+(i>>3),
  // global colgroup g=(i&7)^(i>>3), LDS linearly at c*1024B + i*16B.
  const int srow_in = lane >> 3;                 // 0..7
  const int sg      = (lane & 7) ^ srow_in;      // inverse-swizzled colgroup
  f32x4 acc[4][4] = {};
  for (int k0 = 0; k0 < 1024; k0 += 64) {
    #pragma unroll
    for (int n = 0; n < 4; ++n) {
      const int c = n * 4 + wv;                  // 16 chunks over 4 waves
      const int r = c * 8 + srow_in;
      __builtin_amdgcn_global_load_lds(GPTR(Xb + (size_t)r * 1024 + k0 + sg * 8),
                                       LPTR(&As[c * 512 + lane * 8]), 16, 0, 0);
      __builtin_amdgcn_global_load_lds(GPTR(Wb + (size_t)r * 1024 + k0 + sg * 8),
                                       LPTR(&Bs[c * 512 + lane * 8]), 16, 0, 0);
    }
    __syncthreads();
    const int kq0 = lane >> 4;                   // 0..3
    bf16x8 a4[4][2], b4[4][2];
    #pragma unroll
    for (int mt = 0; mt < 4; ++mt) {
      const int ra = wm * 64 + mt * 16 + (lane & 15);
      #pragma unroll
      for (int h = 0; h < 2; ++h)
        a4[mt][h] = *(const bf16x8*)&As[ra * 64 + (((kq0 + h * 4) ^ (ra & 7)) * 8)];
    }
    #pragma unroll
    for (int nt = 0; nt < 4; ++nt) {
      const int rb = wn * 64 + nt * 16 + (lane & 15);
      #pragma unroll
      for (int h = 0; h < 2; ++h)
        b4[nt][h] = *(const bf16x8*)&Bs[rb * 64 + (((kq0 + h * 4) ^ (rb & 7)) * 8)];
    }
    #pragma unroll
    for (int mt = 0; mt < 4; ++mt)
      #pragma unroll
      for (int nt = 0; nt < 4; ++nt) {
        acc[mt][nt] = __builtin_amdgcn_mfma_f32_16x16x32_bf16(a4[mt][0], b4[nt][0], acc[mt][nt], 0, 0, 0);
        acc[mt][nt] = __builtin_amdgcn_mfma_f32_16x16x32_bf16(a4[mt][1], b4[nt][1], acc[mt][nt], 0, 0, 0);
      }
    __syncthreads();
  }
  #pragma unroll
  for (int mt = 0; mt < 4; ++mt) {
    const int mbase = bm * 128 + wm * 64 + mt * 16 + ((lane >> 4) << 2);
    #pragma unroll
    for (int nt = 0; nt < 4; ++nt) {
      const int n = bn * 128 + wn * 64 + nt * 16 + (lane & 15);
      const float bi = bias[n];
      const int d = n >> 11;
      const int nn = n & 2047;
      const int q = nn >> 9;          // gate
      const int j = nn & 511;         // h column
      const int col = (j >> 4) * 64 + q * 16 + (j & 15);
      #pragma unroll
      for (int r = 0; r < 4; ++r) {
        const int mm = mbase + r;
        const int b = mm >> 9, t = mm & 511;
        gx[((size_t)(d * 512 + t) * 32 + b) * 2048 + col] = f2bf(acc[mt][nt][r] + bi);
      }
    }
  }
}

// ---------------- persistent bidirectional recurrence (round-13 verbatim) ----------------
// 64 blocks: dir = bid>>5, db = bid&31 owns h-cols [db*16, db*16+16).
// hstep layout: [dir][slot s][producer db][row 0..31][16 cols] bf16 — producer stores
// ONE CONTIGUOUS 1KB chunk per step; consumer wave loads 2KB-strided 512B windows.
// Slots pre-memset 0xFF (|h|<1 so a valid pair is never 0xFFFFFFFF).
// s_sleep(16) pre-pays part of the visibility window, probe spin detects, bulk staged
// vmcnt(8)/vmcnt(0) under the MFMA chain, masked sentinel backstops (terminating).
__global__ __launch_bounds__(256, 1) void k_rec(
    const u16* __restrict__ gx, const float* __restrict__ whh,
    u16* __restrict__ xout, u16* hstep)
{
  const int bid = blockIdx.x;
  const int dir = bid >> 5;
  const int db = bid & 31;
  const int j0 = db * 16;
  const int tid = threadIdx.x;
  const int lane = tid & 63;
  const int wv = tid >> 6;
  const int mh = wv >> 1, nh = wv & 1;
  const int R = lane & 15;
  const int ks = lane >> 4;

  __shared__ float G[2][32][68];

  // ---- Whh chunk -> registers (bf16 B-fragments)
  bf16x8 bw[2][16];
  {
    #pragma unroll
    for (int nt = 0; nt < 2; ++nt) {
      const int q = nh * 2 + nt;   // gate: 0=i 1=f 2=g 3=o
      const float* wp = whh + ((size_t)dir * 2048 + q * 512 + j0 + R) * 512 + ks * 8;
      #pragma unroll
      for (int kt = 0; kt < 16; ++kt) {
        float4 v0 = *(const float4*)(wp + kt * 32);
        float4 v1 = *(const float4*)(wp + kt * 32 + 4);
        union { u16 u[8]; bf16x8 v; } t;
        t.u[0] = f2bf(v0.x); t.u[1] = f2bf(v0.y); t.u[2] = f2bf(v0.z); t.u[3] = f2bf(v0.w);
        t.u[4] = f2bf(v1.x); t.u[5] = f2bf(v1.y); t.u[6] = f2bf(v1.z); t.u[7] = f2bf(v1.w);
        bw[nt][kt] = t.v;
      }
    }
  }

  const int eb = tid >> 3;          // batch row for elementwise
  const int pr = (tid & 7) * 2;     // h-col pair within chunk
  float c0 = 0.f, c1 = 0.f;

  const size_t dirbase = (size_t)dir * 512 * 16384;
  // A-frag (kt): producer p = 2*kt + (ks>>1); addr = dirbase + slot + p*512 + row*16 + (ks&1)*8
  const u16* apbase = hstep + dirbase + (size_t)(ks >> 1) * 512 + (mh * 16 + R) * 16 + (ks & 1) * 8;
  // probe: one dword of producer (lane&31)'s chunk (row 31, cols 14-15)
  const u16* prbase = hstep + dirbase + (size_t)(lane & 31) * 512 + 510;
  const u16* gxeb   = gx + ((size_t)dir * 512 * 32 + eb) * 2048 + db * 64 + pr;

  uint32_t gq[4];
  {
    const int t0 = dir ? 511 : 0;
    const uint32_t* g0 = (const uint32_t*)(gxeb + (size_t)t0 * 65536);
    gq[0] = g0[0]; gq[1] = g0[8]; gq[2] = g0[16]; gq[3] = g0[24];
  }

  for (int s = 0; s < 512; ++s) {
    const int tcur = dir ? (511 - s) : s;
    const int gb = s & 1;
    f32x4 acc0 = {0.f,0.f,0.f,0.f}, acc1 = {0.f,0.f,0.f,0.f};

    if (s) {
      const size_t slot = (size_t)(s - 1) * 16384;
      const u16* ap = apbase + slot;
      // ---- sleep-then-probe: let producers' stores become LLC-visible, detect cheaply
      __builtin_amdgcn_s_sleep(16);
      {
        const u16* pp = prbase + slot;
        while (true) {
          uint32_t fv;
          asm volatile("global_load_dword %0, %1, off sc0 sc1\n\ts_waitcnt vmcnt(0)"
                       : "=v"(fv) : "v"(pp) : "memory");
          if (__all((int)(fv != 0xFFFFFFFFu))) break;
        }
      }
      __builtin_amdgcn_sched_barrier(0);
      // ---- bulk A-fragment loads (16 x dwordx4, 2KB stride)
      uint4 afu[16];
      #pragma unroll
      for (int kt = 0; kt < 16; ++kt)
        asm volatile("global_load_dwordx4 %0, %1, off sc0 sc1"
                     : "=v"(afu[kt]) : "v"(ap + kt * 1024) : "memory");
      // ---- stage 1: frags 0..7
      asm volatile("s_waitcnt vmcnt(8)" ::: "memory");
      __builtin_amdgcn_sched_barrier(0);
      while (true) {   // backstop (rare)
        unsigned mask = 0;
        #pragma unroll
        for (int kt = 0; kt < 8; ++kt) {
          int ok = (afu[kt].x != 0xFFFFFFFFu) && (afu[kt].y != 0xFFFFFFFFu) &&
                   (afu[kt].z != 0xFFFFFFFFu) && (afu[kt].w != 0xFFFFFFFFu);
          if (!__all(ok)) mask |= 1u << kt;
        }
        if (!mask) break;
        #pragma unroll
        for (int kt = 0; kt < 8; ++kt)
          if (mask & (1u << kt))
            asm volatile("global_load_dwordx4 %0, %1, off sc0 sc1"
                         : "=v"(afu[kt]) : "v"(ap + kt * 1024) : "memory");
        asm volatile("s_waitcnt vmcnt(0)" ::: "memory");
        __builtin_amdgcn_sched_barrier(0);
      }
      f32x4 a0 = {0.f,0.f,0.f,0.f}, a1 = {0.f,0.f,0.f,0.f};
      f32x4 b0 = {0.f,0.f,0.f,0.f}, b1 = {0.f,0.f,0.f,0.f};
      #pragma unroll
      for (int kt = 0; kt < 8; kt += 2) {
        bf16x8 x = __builtin_bit_cast(bf16x8, afu[kt]);
        bf16x8 y = __builtin_bit_cast(bf16x8, afu[kt + 1]);
        a0 = __builtin_amdgcn_mfma_f32_16x16x32_bf16(x, bw[0][kt],     a0, 0, 0, 0);
        a1 = __builtin_amdgcn_mfma_f32_16x16x32_bf16(x, bw[1][kt],     a1, 0, 0, 0);
        b0 = __builtin_amdgcn_mfma_f32_16x16x32_bf16(y, bw[0][kt + 1], b0, 0, 0, 0);
        b1 = __builtin_amdgcn_mfma_f32_16x16x32_bf16(y, bw[1][kt + 1], b1, 0, 0, 0);
      }
      // ---- stage 2: frags 8..15
      asm volatile("s_waitcnt vmcnt(0)" ::: "memory");
      __builtin_amdgcn_sched_barrier(0);
      while (true) {   // backstop (rare)
        unsigned mask = 0;
        #pragma unroll
        for (int kt = 8; kt < 16; ++kt) {
          int ok = (afu[kt].x != 0xFFFFFFFFu) && (afu[kt].y != 0xFFFFFFFFu) &&
                   (afu[kt].z != 0xFFFFFFFFu) && (afu[kt].w != 0xFFFFFFFFu);
          if (!__all(ok)) mask |= 1u << (kt - 8);
        }
        if (!mask) break;
        #pragma unroll
        for (int kt = 8; kt < 16; ++kt)
          if (mask & (1u << (kt - 8)))
            asm volatile("global_load_dwordx4 %0, %1, off sc0 sc1"
                         : "=v"(afu[kt]) : "v"(ap + kt * 1024) : "memory");
        asm volatile("s_waitcnt vmcnt(0)" ::: "memory");
        __builtin_amdgcn_sched_barrier(0);
      }
      #pragma unroll
      for (int kt = 8; kt < 16; kt += 2) {
        bf16x8 x = __builtin_bit_cast(bf16x8, afu[kt]);
        bf16x8 y = __builtin_bit_cast(bf16x8, afu[kt + 1]);
        a0 = __builtin_amdgcn_mfma_f32_16x16x32_bf16(x, bw[0][kt],     a0, 0, 0, 0);
        a1 = __builtin_amdgcn_mfma_f32_16x16x32_bf16(x, bw[1][kt],     a1, 0, 0, 0);
        b0 = __builtin_amdgcn_mfma_f32_16x16x32_bf16(y, bw[0][kt + 1], b0, 0, 0, 0);
        b1 = __builtin_amdgcn_mfma_f32_16x16x32_bf16(y, bw[1][kt + 1], b1, 0, 0, 0);
      }
      acc0 = a0 + b0;
      acc1 = a1 + b1;
    }

    #pragma unroll
    for (int r = 0; r < 4; ++r) {
      G[gb][mh * 16 + (lane >> 4) * 4 + r][nh * 32 + (lane & 15)]      = acc0[r];
      G[gb][mh * 16 + (lane >> 4) * 4 + r][nh * 32 + 16 + (lane & 15)] = acc1[r];
    }
    __syncthreads();                                   // G[gb] complete

    // ---- elementwise LSTM cell for (eb, j0+pr) and (eb, j0+pr+1)
    {
      float i0 = G[gb][eb][pr]      + bf2f((u16)(gq[0] & 0xFFFF));
      float i1 = G[gb][eb][pr + 1]  + bf2f((u16)(gq[0] >> 16));
      float f0 = G[gb][eb][pr + 16] + bf2f((u16)(gq[1] & 0xFFFF));
      float f1 = G[gb][eb][pr + 17] + bf2f((u16)(gq[1] >> 16));
      float g0 = G[gb][eb][pr + 32] + bf2f((u16)(gq[2] & 0xFFFF));
      float g1 = G[gb][eb][pr + 33] + bf2f((u16)(gq[2] >> 16));
      float o0 = G[gb][eb][pr + 48] + bf2f((u16)(gq[3] & 0xFFFF));
      float o1 = G[gb][eb][pr + 49] + bf2f((u16)(gq[3] >> 16));
      c0 = sigf(f0) * c0 + sigf(i0) * tanhf_(g0);
      c1 = sigf(f1) * c1 + sigf(i1) * tanhf_(g1);
      float h0 = sigf(o0) * tanhf_(c0);
      float h1 = sigf(o1) * tanhf_(c1);
      uint32_t hp = (uint32_t)f2bf(h0) | ((uint32_t)f2bf(h1) << 16);
      // contiguous 1KB producer chunk: [slot s][db][eb][pr]
      u16* hdst = hstep + dirbase + (size_t)s * 16384 + (size_t)db * 512 + eb * 16 + pr;
      asm volatile("global_store_dword %0, %1, off sc0 sc1"
                   :: "v"(hdst), "v"(hp) : "memory");
      *(uint32_t*)(xout + ((size_t)eb * 512 + tcur) * 1024 + dir * 512 + j0 + pr) = hp;
    }
    // ---- software-pipelined gx for next step (plain loads; drained by next poll's vmcnt(0))
    if (s < 511) {
      const int tn = dir ? (511 - (s + 1)) : (s + 1);
      const uint32_t* gn = (const uint32_t*)(gxeb + (size_t)tn * 65536);
      gq[0] = gn[0]; gq[1] = gn[8]; gq[2] = gn[16]; gq[3] = gn[24];
    }
    // no trailing barrier: G ping-pong, next step writes G[gb^1]
  }
}

// ---------------- classifier stage 1 ----------------
__global__ void k_cls1(const u16* __restrict__ x3, const int* __restrict__ idxb,
                       const float* __restrict__ w1, const float* __restrict__ b1,
                       float* __restrict__ h1) {
  __shared__ u16 hid[32][1024];
  const int tid = threadIdx.x;
  for (int g = tid; g < 4096; g += 256) {
    const int b = g >> 7;
    const int c8 = (g & 127) * 8;
    *(uint4*)&hid[b][c8] = *(const uint4*)(x3 + ((size_t)b * 512 + idxb[b]) * 1024 + c8);
  }
  __syncthreads();
  for (int p = tid; p < 1024; p += 256) {
    const int j = blockIdx.x * 32 + (p >> 5);
    const int b = p & 31;
    const float4* wr = (const float4*)(w1 + (size_t)j * 1024);
    float s = 0.f;
    for (int k4 = 0; k4 < 256; ++k4) {
      float4 wv = wr[k4];
      const int k = k4 * 4;
      s += bf2f(hid[b][k]) * wv.x + bf2f(hid[b][k + 1]) * wv.y
         + bf2f(hid[b][k + 2]) * wv.z + bf2f(hid[b][k + 3]) * wv.w;
    }
    h1[b * 512 + j] = tanhf_(s + b1[j]);
  }
}

// ---------------- classifier stage 2: BCE-with-logits mean ----------------
__global__ void k_cls2(const float* __restrict__ h1, const float* __restrict__ w2,
                       const float* __restrict__ b2, const float* __restrict__ label,
                       float* __restrict__ out) {
  const int lane = threadIdx.x;   // 64
  float loss = 0.f;
  for (int b = 0; b < 32; ++b) {
    float s = 0.f;
    for (int k = lane; k < 512; k += 64) s += h1[b * 512 + k] * w2[k];
    for (int off = 32; off; off >>= 1) s += __shfl_down(s, off);
    if (lane == 0) {
      const float z = s + b2[0];
      const float y = label[b];
      const float sp = fmaxf(z, 0.f) + log1pf(__expf(-fabsf(z)));
      loss += sp - z * y;
    }
  }
  if (lane == 0) out[0] = loss / 32.0f;
}

extern "C" void kernel_launch(void* const* d_in, const int* in_sizes, int n_in,
                              void* d_out, int out_size, void* d_ws, size_t ws_size,
                              hipStream_t stream) {
  const int*   seq   = (const int*)  d_in[0];
  const float* label = (const float*)d_in[1];
  const float* wemb  = (const float*)d_in[2];
  const float* wih   = (const float*)d_in[3];
  const float* whh   = (const float*)d_in[4];
  const float* bb    = (const float*)d_in[5];
  const float* w1    = (const float*)d_in[6];
  const float* b1    = (const float*)d_in[7];
  const float* w2    = (const float*)d_in[8];
  const float* b2    = (const float*)d_in[9];

  u16* x1   = (u16*)d_ws;                       // [32][512][1024] bf16 (hstep region for layer1)
  u16* x2   = x1 + (size_t)16777216;            // [32][512][1024] bf16 (hstep region for layer2)
  u16* gxb  = x2 + (size_t)16777216;            // [2][512][32][2048] bf16
  u16* wb   = gxb + (size_t)67108864;           // [4096][1024] bf16
  float* h1 = (float*)(wb + 4194304);           // [32][512] f32
  int* idxb = (int*)(h1 + 16384);               // [32]

  // layer 1
  k_emb<<<16384, 256, 0, stream>>>(seq, wemb, x1);
  k_idx<<<1, 256, 0, stream>>>(seq, idxb);
  k_cast<<<4096, 256, 0, stream>>>(wih, wb);
  k_gemm<<<dim3(128, 32), 256, 0, stream>>>(x1, wb, bb, gxb);
  hipMemsetAsync(x1, 0xFF, (size_t)33554432, stream);      // hstep sentinel (layer1)
  k_rec<<<64, 256, 0, stream>>>(gxb, whh, x2, x1);
  // layer 2
  k_cast<<<4096, 256, 0, stream>>>(wih + 4194304, wb);
  k_gemm<<<dim3(128, 32), 256, 0, stream>>>(x2, wb, bb + 4096, gxb);
  hipMemsetAsync(x2, 0xFF, (size_t)33554432, stream);      // hstep sentinel (layer2)
  k_rec<<<64, 256, 0, stream>>>(gxb, whh + 2097152, x1, x2);
  // head
  k_cls1<<<16, 256, 0, stream>>>(x1, idxb, w1, b1, h1);
  k_cls2<<<1, 64, 0, stream>>>(h1, w2, b2, label, (float*)d_out);
}

// Round 16
// 3780.964 us; speedup vs baseline: 1.1562x; 1.0578x over previous
//
#include <hip/hip_runtime.h>
#include <stdint.h>

typedef unsigned short u16;
typedef __bf16 bf16x8 __attribute__((ext_vector_type(8)));
typedef float  f32x4  __attribute__((ext_vector_type(4)));

#define GPTR(p) ((const __attribute__((address_space(1))) void*)(p))
#define LPTR(p) ((__attribute__((address_space(3))) void*)(p))
#define GVALID(X) (int)((((X) & 0xFFFFu) != 0xFFFFu) & (((X) >> 16) != 0xFFFFu))

__device__ __forceinline__ u16 f2bf(float f) {
  uint32_t u = __float_as_uint(f);
  u += 0x7FFFu + ((u >> 16) & 1u);
  return (u16)(u >> 16);
}
__device__ __forceinline__ float bf2f(u16 h) {
  return __uint_as_float(((uint32_t)h) << 16);
}
__device__ __forceinline__ float sigf(float x) { return 1.0f / (1.0f + __expf(-x)); }
__device__ __forceinline__ float tanhf_(float x) { return 1.0f - 2.0f / (__expf(2.0f * x) + 1.0f); }

// ---------------- embedding gather: X layout [t][b][1024] ----------------
__global__ void k_emb(const int* __restrict__ seq, const float* __restrict__ wemb,
                      u16* __restrict__ x1) {
  const int row = blockIdx.x;          // 0..16383 = b*512+t
  const int tok = seq[row];
  const int b = row >> 9, t = row & 511;
  float4 v = ((const float4*)(wemb + (size_t)tok * 1024))[threadIdx.x];
  uint32_t lo = (uint32_t)f2bf(v.x) | ((uint32_t)f2bf(v.y) << 16);
  uint32_t hi = (uint32_t)f2bf(v.z) | ((uint32_t)f2bf(v.w) << 16);
  *(uint2*)(x1 + ((size_t)t * 32 + b) * 1024 + threadIdx.x * 4) = make_uint2(lo, hi);
}

// ---------------- marker index per row ----------------
__global__ void k_idx(const int* __restrict__ seq, int* __restrict__ idxb) {
  const int tid = threadIdx.x;         // 256
  const int b = tid >> 3, part = tid & 7;
  for (int t = part * 64; t < part * 64 + 64; ++t)
    if (seq[b * 512 + t] == 50000) idxb[b] = t;
}

// ---------------- cast 4096x1024 f32 -> bf16 ----------------
__global__ void k_cast(const float* __restrict__ src, u16* __restrict__ dst) {
  const int i = blockIdx.x * 256 + threadIdx.x;
  float4 v = ((const float4*)src)[i];
  uint32_t lo = (uint32_t)f2bf(v.x) | ((uint32_t)f2bf(v.y) << 16);
  uint32_t hi = (uint32_t)f2bf(v.z) | ((uint32_t)f2bf(v.w) << 16);
  *(uint2*)(dst + (size_t)i * 4) = make_uint2(lo, hi);
}

// ================= fused gemm + persistent recurrence =================
// blocks [0, rec_blocks): recurrence (r15 structure + gq sentinel-validity).
// blocks [rec_blocks, ...): gemm, X layout [t][b][1024] (m = t*32+b), m-tiles walked
// ends-first so t=0 / t=511 gx become valid earliest. gx memset 0xFF by host when
// overlapped; a valid gx bf16 is finite (never 0xFFFF) -> per-half sentinel checks.
// All waits terminate: gemm blocks never wait; rec waits only on data gemm/rec produce.
__global__ __launch_bounds__(256, 1) void k_fused(
    const int rec_blocks,
    const u16* __restrict__ X, const u16* __restrict__ W,
    const float* __restrict__ bias, u16* __restrict__ gx,
    const float* __restrict__ whh, u16* __restrict__ xout, u16* hstep)
{
  __shared__ u16 smem[16384];   // gemm: As|Bs (32KB). rec: G[2][32][68] f32 (17.4KB)
  const int tid = threadIdx.x;

  if ((int)blockIdx.x >= rec_blocks) {
    // ---------------- GEMM (r15 BK=64 + both-sides swizzle) ----------------
    u16* As = smem;
    u16* Bs = smem + 8192;
    const int bk = blockIdx.x - rec_blocks;
    const int bn = bk & 31;
    const int bmo = bk >> 5;
    const int bm = (bmo & 1) ? (127 - (bmo >> 1)) : (bmo >> 1);   // ends-first
    const int lane = tid & 63;
    const int wv = tid >> 6;
    const int wm = wv >> 1, wn = wv & 1;
    const u16* Xb = X + (size_t)bm * 128 * 1024;
    const u16* Wb = W + (size_t)bn * 128 * 1024;
    const int srow_in = lane >> 3;
    const int sg      = (lane & 7) ^ srow_in;      // inverse-swizzled colgroup
    f32x4 acc[4][4] = {};
    for (int k0 = 0; k0 < 1024; k0 += 64) {
      #pragma unroll
      for (int n = 0; n < 4; ++n) {
        const int c = n * 4 + wv;
        const int r = c * 8 + srow_in;
        __builtin_amdgcn_global_load_lds(GPTR(Xb + (size_t)r * 1024 + k0 + sg * 8),
                                         LPTR(&As[c * 512 + lane * 8]), 16, 0, 0);
        __builtin_amdgcn_global_load_lds(GPTR(Wb + (size_t)r * 1024 + k0 + sg * 8),
                                         LPTR(&Bs[c * 512 + lane * 8]), 16, 0, 0);
      }
      __syncthreads();
      const int kq0 = lane >> 4;
      bf16x8 a4[4][2], b4[4][2];
      #pragma unroll
      for (int mt = 0; mt < 4; ++mt) {
        const int ra = wm * 64 + mt * 16 + (lane & 15);
        #pragma unroll
        for (int h = 0; h < 2; ++h)
          a4[mt][h] = *(const bf16x8*)&As[ra * 64 + (((kq0 + h * 4) ^ (ra & 7)) * 8)];
      }
      #pragma unroll
      for (int nt = 0; nt < 4; ++nt) {
        const int rb = wn * 64 + nt * 16 + (lane & 15);
        #pragma unroll
        for (int h = 0; h < 2; ++h)
          b4[nt][h] = *(const bf16x8*)&Bs[rb * 64 + (((kq0 + h * 4) ^ (rb & 7)) * 8)];
      }
      #pragma unroll
      for (int mt = 0; mt < 4; ++mt)
        #pragma unroll
        for (int nt = 0; nt < 4; ++nt) {
          acc[mt][nt] = __builtin_amdgcn_mfma_f32_16x16x32_bf16(a4[mt][0], b4[nt][0], acc[mt][nt], 0, 0, 0);
          acc[mt][nt] = __builtin_amdgcn_mfma_f32_16x16x32_bf16(a4[mt][1], b4[nt][1], acc[mt][nt], 0, 0, 0);
        }
      __syncthreads();
    }
    #pragma unroll
    for (int mt = 0; mt < 4; ++mt) {
      const int mbase = bm * 128 + wm * 64 + mt * 16 + ((lane >> 4) << 2);
      #pragma unroll
      for (int nt = 0; nt < 4; ++nt) {
        const int n = bn * 128 + wn * 64 + nt * 16 + (lane & 15);
        const float bi = bias[n];
        const int d = n >> 11;
        const int nn = n & 2047;
        const int q = nn >> 9;
        const int j = nn & 511;
        const int col = (j >> 4) * 64 + q * 16 + (j & 15);
        #pragma unroll
        for (int r = 0; r < 4; ++r) {
          const int mm = mbase + r;
          const int t = mm >> 5, b = mm & 31;          // m = t*32+b
          gx[((size_t)(d * 512 + t) * 32 + b) * 2048 + col] = f2bf(acc[mt][nt][r] + bi);
        }
      }
    }
    return;
  }

  // ---------------- RECURRENCE (r13/r15 verbatim + gq validity) ----------------
  float (*G)[32][68] = (float(*)[32][68])smem;
  const int bid = blockIdx.x;
  const int dir = bid >> 5;
  const int db = bid & 31;
  const int j0 = db * 16;
  const int lane = tid & 63;
  const int wv = tid >> 6;
  const int mh = wv >> 1, nh = wv & 1;
  const int R = lane & 15;
  const int ks = lane >> 4;

  bf16x8 bw[2][16];
  {
    #pragma unroll
    for (int nt = 0; nt < 2; ++nt) {
      const int q = nh * 2 + nt;
      const float* wp = whh + ((size_t)dir * 2048 + q * 512 + j0 + R) * 512 + ks * 8;
      #pragma unroll
      for (int kt = 0; kt < 16; ++kt) {
        float4 v0 = *(const float4*)(wp + kt * 32);
        float4 v1 = *(const float4*)(wp + kt * 32 + 4);
        union { u16 u[8]; bf16x8 v; } t;
        t.u[0] = f2bf(v0.x); t.u[1] = f2bf(v0.y); t.u[2] = f2bf(v0.z); t.u[3] = f2bf(v0.w);
        t.u[4] = f2bf(v1.x); t.u[5] = f2bf(v1.y); t.u[6] = f2bf(v1.z); t.u[7] = f2bf(v1.w);
        bw[nt][kt] = t.v;
      }
    }
  }

  const int eb = tid >> 3;
  const int pr = (tid & 7) * 2;
  float c0 = 0.f, c1 = 0.f;

  const size_t dirbase = (size_t)dir * 512 * 16384;
  const u16* apbase = hstep + dirbase + (size_t)(ks >> 1) * 512 + (mh * 16 + R) * 16 + (ks & 1) * 8;
  const u16* prbase = hstep + dirbase + (size_t)(lane & 31) * 512 + 510;
  const u16* gxeb   = gx + ((size_t)dir * 512 * 32 + eb) * 2048 + db * 64 + pr;

  uint32_t gq[4];
  {
    const int t0 = dir ? 511 : 0;
    const uint32_t* g0 = (const uint32_t*)(gxeb + (size_t)t0 * 65536);
    gq[0] = g0[0]; gq[1] = g0[8]; gq[2] = g0[16]; gq[3] = g0[24];
  }

  for (int s = 0; s < 512; ++s) {
    const int tcur = dir ? (511 - s) : s;
    const int gb = s & 1;
    f32x4 acc0 = {0.f,0.f,0.f,0.f}, acc1 = {0.f,0.f,0.f,0.f};

    if (s) {
      const size_t slot = (size_t)(s - 1) * 16384;
      const u16* ap = apbase + slot;
      __builtin_amdgcn_s_sleep(16);
      {
        const u16* pp = prbase + slot;
        while (true) {
          uint32_t fv;
          asm volatile("global_load_dword %0, %1, off sc0 sc1\n\ts_waitcnt vmcnt(0)"
                       : "=v"(fv) : "v"(pp) : "memory");
          if (__all((int)(fv != 0xFFFFFFFFu))) break;
        }
      }
      __builtin_amdgcn_sched_barrier(0);
      uint4 afu[16];
      #pragma unroll
      for (int kt = 0; kt < 16; ++kt)
        asm volatile("global_load_dwordx4 %0, %1, off sc0 sc1"
                     : "=v"(afu[kt]) : "v"(ap + kt * 1024) : "memory");
      asm volatile("s_waitcnt vmcnt(8)" ::: "memory");
      __builtin_amdgcn_sched_barrier(0);
      while (true) {   // backstop frags 0..7 (rare)
        unsigned mask = 0;
        #pragma unroll
        for (int kt = 0; kt < 8; ++kt) {
          int ok = (afu[kt].x != 0xFFFFFFFFu) && (afu[kt].y != 0xFFFFFFFFu) &&
                   (afu[kt].z != 0xFFFFFFFFu) && (afu[kt].w != 0xFFFFFFFFu);
          if (!__all(ok)) mask |= 1u << kt;
        }
        if (!mask) break;
        #pragma unroll
        for (int kt = 0; kt < 8; ++kt)
          if (mask & (1u << kt))
            asm volatile("global_load_dwordx4 %0, %1, off sc0 sc1"
                         : "=v"(afu[kt]) : "v"(ap + kt * 1024) : "memory");
        asm volatile("s_waitcnt vmcnt(0)" ::: "memory");
        __builtin_amdgcn_sched_barrier(0);
      }
      f32x4 a0 = {0.f,0.f,0.f,0.f}, a1 = {0.f,0.f,0.f,0.f};
      f32x4 b0 = {0.f,0.f,0.f,0.f}, b1 = {0.f,0.f,0.f,0.f};
      #pragma unroll
      for (int kt = 0; kt < 8; kt += 2) {
        bf16x8 x = __builtin_bit_cast(bf16x8, afu[kt]);
        bf16x8 y = __builtin_bit_cast(bf16x8, afu[kt + 1]);
        a0 = __builtin_amdgcn_mfma_f32_16x16x32_bf16(x, bw[0][kt],     a0, 0, 0, 0);
        a1 = __builtin_amdgcn_mfma_f32_16x16x32_bf16(x, bw[1][kt],     a1, 0, 0, 0);
        b0 = __builtin_amdgcn_mfma_f32_16x16x32_bf16(y, bw[0][kt + 1], b0, 0, 0, 0);
        b1 = __builtin_amdgcn_mfma_f32_16x16x32_bf16(y, bw[1][kt + 1], b1, 0, 0, 0);
      }
      asm volatile("s_waitcnt vmcnt(0)" ::: "memory");
      __builtin_amdgcn_sched_barrier(0);
      while (true) {   // backstop frags 8..15 (rare)
        unsigned mask = 0;
        #pragma unroll
        for (int kt = 8; kt < 16; ++kt) {
          int ok = (afu[kt].x != 0xFFFFFFFFu) && (afu[kt].y != 0xFFFFFFFFu) &&
                   (afu[kt].z != 0xFFFFFFFFu) && (afu[kt].w != 0xFFFFFFFFu);
          if (!__all(ok)) mask |= 1u << (kt - 8);
        }
        if (!mask) break;
        #pragma unroll
        for (int kt = 8; kt < 16; ++kt)
          if (mask & (1u << (kt - 8)))
            asm volatile("global_load_dwordx4 %0, %1, off sc0 sc1"
                         : "=v"(afu[kt]) : "v"(ap + kt * 1024) : "memory");
        asm volatile("s_waitcnt vmcnt(0)" ::: "memory");
        __builtin_amdgcn_sched_barrier(0);
      }
      #pragma unroll
      for (int kt = 8; kt < 16; kt += 2) {
        bf16x8 x = __builtin_bit_cast(bf16x8, afu[kt]);
        bf16x8 y = __builtin_bit_cast(bf16x8, afu[kt + 1]);
        a0 = __builtin_amdgcn_mfma_f32_16x16x32_bf16(x, bw[0][kt],     a0, 0, 0, 0);
        a1 = __builtin_amdgcn_mfma_f32_16x16x32_bf16(x, bw[1][kt],     a1, 0, 0, 0);
        b0 = __builtin_amdgcn_mfma_f32_16x16x32_bf16(y, bw[0][kt + 1], b0, 0, 0, 0);
        b1 = __builtin_amdgcn_mfma_f32_16x16x32_bf16(y, bw[1][kt + 1], b1, 0, 0, 0);
      }
      acc0 = a0 + b0;
      acc1 = a1 + b1;
    }

    #pragma unroll
    for (int r = 0; r < 4; ++r) {
      G[gb][mh * 16 + (lane >> 4) * 4 + r][nh * 32 + (lane & 15)]      = acc0[r];
      G[gb][mh * 16 + (lane >> 4) * 4 + r][nh * 32 + 16 + (lane & 15)] = acc1[r];
    }
    __syncthreads();

    // ---- gq validity (gemm may lag when overlapped; serial path passes instantly)
    {
      int ok = GVALID(gq[0]) & GVALID(gq[1]) & GVALID(gq[2]) & GVALID(gq[3]);
      if (!__all(ok)) {
        const u16* gp = gxeb + (size_t)tcur * 65536;
        while (true) {
          asm volatile("global_load_dword %0, %1, off sc0 sc1" : "=v"(gq[0]) : "v"(gp +  0) : "memory");
          asm volatile("global_load_dword %0, %1, off sc0 sc1" : "=v"(gq[1]) : "v"(gp + 16) : "memory");
          asm volatile("global_load_dword %0, %1, off sc0 sc1" : "=v"(gq[2]) : "v"(gp + 32) : "memory");
          asm volatile("global_load_dword %0, %1, off sc0 sc1" : "=v"(gq[3]) : "v"(gp + 48) : "memory");
          asm volatile("s_waitcnt vmcnt(0)" ::: "memory");
          __builtin_amdgcn_sched_barrier(0);
          ok = GVALID(gq[0]) & GVALID(gq[1]) & GVALID(gq[2]) & GVALID(gq[3]);
          if (__all(ok)) break;
        }
      }
    }

    // ---- elementwise LSTM cell
    {
      float i0 = G[gb][eb][pr]      + bf2f((u16)(gq[0] & 0xFFFF));
      float i1 = G[gb][eb][pr + 1]  + bf2f((u16)(gq[0] >> 16));
      float f0 = G[gb][eb][pr + 16] + bf2f((u16)(gq[1] & 0xFFFF));
      float f1 = G[gb][eb][pr + 17] + bf2f((u16)(gq[1] >> 16));
      float g0 = G[gb][eb][pr + 32] + bf2f((u16)(gq[2] & 0xFFFF));
      float g1 = G[gb][eb][pr + 33] + bf2f((u16)(gq[2] >> 16));
      float o0 = G[gb][eb][pr + 48] + bf2f((u16)(gq[3] & 0xFFFF));
      float o1 = G[gb][eb][pr + 49] + bf2f((u16)(gq[3] >> 16));
      c0 = sigf(f0) * c0 + sigf(i0) * tanhf_(g0);
      c1 = sigf(f1) * c1 + sigf(i1) * tanhf_(g1);
      float h0 = sigf(o0) * tanhf_(c0);
      float h1 = sigf(o1) * tanhf_(c1);
      uint32_t hp = (uint32_t)f2bf(h0) | ((uint32_t)f2bf(h1) << 16);
      u16* hdst = hstep + dirbase + (size_t)s * 16384 + (size_t)db * 512 + eb * 16 + pr;
      asm volatile("global_store_dword %0, %1, off sc0 sc1"
                   :: "v"(hdst), "v"(hp) : "memory");
      *(uint32_t*)(xout + ((size_t)tcur * 32 + eb) * 1024 + dir * 512 + j0 + pr) = hp;   // [t][b][1024]
    }
    if (s < 511) {
      const int tn = dir ? (511 - (s + 1)) : (s + 1);
      const uint32_t* gn = (const uint32_t*)(gxeb + (size_t)tn * 65536);
      gq[0] = gn[0]; gq[1] = gn[8]; gq[2] = gn[16]; gq[3] = gn[24];
    }
  }
}

// ---------------- classifier stage 1 (x3 layout [t][b][1024]) ----------------
__global__ void k_cls1(const u16* __restrict__ x3, const int* __restrict__ idxb,
                       const float* __restrict__ w1, const float* __restrict__ b1,
                       float* __restrict__ h1) {
  __shared__ u16 hid[32][1024];
  const int tid = threadIdx.x;
  for (int g = tid; g < 4096; g += 256) {
    const int b = g >> 7;
    const int c8 = (g & 127) * 8;
    *(uint4*)&hid[b][c8] = *(const uint4*)(x3 + ((size_t)idxb[b] * 32 + b) * 1024 + c8);
  }
  __syncthreads();
  for (int p = tid; p < 1024; p += 256) {
    const int j = blockIdx.x * 32 + (p >> 5);
    const int b = p & 31;
    const float4* wr = (const float4*)(w1 + (size_t)j * 1024);
    float s = 0.f;
    for (int k4 = 0; k4 < 256; ++k4) {
      float4 wv = wr[k4];
      const int k = k4 * 4;
      s += bf2f(hid[b][k]) * wv.x + bf2f(hid[b][k + 1]) * wv.y
         + bf2f(hid[b][k + 2]) * wv.z + bf2f(hid[b][k + 3]) * wv.w;
    }
    h1[b * 512 + j] = tanhf_(s + b1[j]);
  }
}

// ---------------- classifier stage 2: BCE-with-logits mean ----------------
__global__ void k_cls2(const float* __restrict__ h1, const float* __restrict__ w2,
                       const float* __restrict__ b2, const float* __restrict__ label,
                       float* __restrict__ out) {
  const int lane = threadIdx.x;   // 64
  float loss = 0.f;
  for (int b = 0; b < 32; ++b) {
    float s = 0.f;
    for (int k = lane; k < 512; k += 64) s += h1[b * 512 + k] * w2[k];
    for (int off = 32; off; off >>= 1) s += __shfl_down(s, off);
    if (lane == 0) {
      const float z = s + b2[0];
      const float y = label[b];
      const float sp = fmaxf(z, 0.f) + log1pf(__expf(-fabsf(z)));
      loss += sp - z * y;
    }
  }
  if (lane == 0) out[0] = loss / 32.0f;
}

extern "C" void kernel_launch(void* const* d_in, const int* in_sizes, int n_in,
                              void* d_out, int out_size, void* d_ws, size_t ws_size,
                              hipStream_t stream) {
  const int*   seq   = (const int*)  d_in[0];
  const float* label = (const float*)d_in[1];
  const float* wemb  = (const float*)d_in[2];
  const float* wih   = (const float*)d_in[3];
  const float* whh   = (const float*)d_in[4];
  const float* bb    = (const float*)d_in[5];
  const float* w1    = (const float*)d_in[6];
  const float* b1    = (const float*)d_in[7];
  const float* w2    = (const float*)d_in[8];
  const float* b2    = (const float*)d_in[9];

  u16* x1   = (u16*)d_ws;                       // [512][32][1024] bf16
  u16* x2   = x1 + (size_t)16777216;            // [512][32][1024] bf16
  u16* gxb  = x2 + (size_t)16777216;            // [2][512][32][2048] bf16
  u16* wb1  = gxb + (size_t)67108864;           // [4096][1024] bf16
  float* h1 = (float*)(wb1 + 4194304);          // [32][512] f32
  int* idxb = (int*)(h1 + 16384);               // [32]
  u16* wb2  = (u16*)(idxb + 32);                // [4096][1024] bf16  (fused path only)
  u16* hs   = wb2 + (size_t)4194304;            // [2][512][32][32][16] bf16 (fused only)
  const size_t need = (size_t)((char*)(hs + 16777216) - (char*)d_ws);
  const bool fused = ws_size >= need;

  k_emb<<<16384, 256, 0, stream>>>(seq, wemb, x1);
  k_idx<<<1, 256, 0, stream>>>(seq, idxb);
  k_cast<<<4096, 256, 0, stream>>>(wih, wb1);

  if (fused) {
    k_cast<<<4096, 256, 0, stream>>>(wih + 4194304, wb2);
    // layer 1 (gemm ∥ rec)
    hipMemsetAsync(gxb, 0xFF, (size_t)134217728, stream);
    hipMemsetAsync(hs, 0xFF, (size_t)33554432, stream);
    k_fused<<<64 + 4096, 256, 0, stream>>>(64, x1, wb1, bb, gxb, whh, x2, hs);
    // layer 2 (gemm ∥ rec)
    hipMemsetAsync(gxb, 0xFF, (size_t)134217728, stream);
    hipMemsetAsync(hs, 0xFF, (size_t)33554432, stream);
    k_fused<<<64 + 4096, 256, 0, stream>>>(64, x2, wb2, bb + 4096, gxb, whh + 2097152, x1, hs);
  } else {
    // serial fallback (r15 structure; hstep overlays dead X buffers)
    k_fused<<<4096, 256, 0, stream>>>(0, x1, wb1, bb, gxb, whh, x2, x1);
    hipMemsetAsync(x1, 0xFF, (size_t)33554432, stream);
    k_fused<<<64, 256, 0, stream>>>(64, x1, wb1, bb, gxb, whh, x2, x1);
    k_cast<<<4096, 256, 0, stream>>>(wih + 4194304, wb1);
    k_fused<<<4096, 256, 0, stream>>>(0, x2, wb1, bb + 4096, gxb, whh + 2097152, x1, x2);
    hipMemsetAsync(x2, 0xFF, (size_t)33554432, stream);
    k_fused<<<64, 256, 0, stream>>>(64, x2, wb1, bb + 4096, gxb, whh + 2097152, x1, x2);
  }
  k_cls1<<<16, 256, 0, stream>>>(x1, idxb, w1, b1, h1);
  k_cls2<<<1, 64, 0, stream>>>(h1, w2, b2, label, (float*)d_out);
}

// Round 17
// 3778.691 us; speedup vs baseline: 1.1569x; 1.0006x over previous
//
#include <hip/hip_runtime.h>
#include <stdint.h>

typedef unsigned short u16;
typedef __bf16 bf16x8 __attribute__((ext_vector_type(8)));
typedef float  f32x4  __attribute__((ext_vector_type(4)));

#define GPTR(p) ((const __attribute__((address_space(1))) void*)(p))
#define LPTR(p) ((__attribute__((address_space(3))) void*)(p))
#define GVALID(X) (int)((((X) & 0xFFFFu) != 0xFFFFu) & (((X) >> 16) != 0xFFFFu))

__device__ __forceinline__ u16 f2bf(float f) {
  uint32_t u = __float_as_uint(f);
  u += 0x7FFFu + ((u >> 16) & 1u);
  return (u16)(u >> 16);
}
__device__ __forceinline__ float bf2f(u16 h) {
  return __uint_as_float(((uint32_t)h) << 16);
}
__device__ __forceinline__ float sigf(float x) { return 1.0f / (1.0f + __expf(-x)); }
__device__ __forceinline__ float tanhf_(float x) { return 1.0f - 2.0f / (__expf(2.0f * x) + 1.0f); }

// ---------------- embedding gather: X layout [t][b][1024] ----------------
__global__ void k_emb(const int* __restrict__ seq, const float* __restrict__ wemb,
                      u16* __restrict__ x1) {
  const int row = blockIdx.x;          // 0..16383 = b*512+t
  const int tok = seq[row];
  const int b = row >> 9, t = row & 511;
  float4 v = ((const float4*)(wemb + (size_t)tok * 1024))[threadIdx.x];
  uint32_t lo = (uint32_t)f2bf(v.x) | ((uint32_t)f2bf(v.y) << 16);
  uint32_t hi = (uint32_t)f2bf(v.z) | ((uint32_t)f2bf(v.w) << 16);
  *(uint2*)(x1 + ((size_t)t * 32 + b) * 1024 + threadIdx.x * 4) = make_uint2(lo, hi);
}

// ---------------- cast f32 -> bf16 (count*4 floats) ----------------
__global__ void k_cast(const float* __restrict__ src, u16* __restrict__ dst) {
  const int i = blockIdx.x * 256 + threadIdx.x;
  float4 v = ((const float4*)src)[i];
  uint32_t lo = (uint32_t)f2bf(v.x) | ((uint32_t)f2bf(v.y) << 16);
  uint32_t hi = (uint32_t)f2bf(v.z) | ((uint32_t)f2bf(v.w) << 16);
  *(uint2*)(dst + (size_t)i * 4) = make_uint2(lo, hi);
}

// ================= fused gemm + persistent recurrence (r16 verbatim) =================
__global__ __launch_bounds__(256, 1) void k_fused(
    const int rec_blocks,
    const u16* __restrict__ X, const u16* __restrict__ W,
    const float* __restrict__ bias, u16* __restrict__ gx,
    const float* __restrict__ whh, u16* __restrict__ xout, u16* hstep)
{
  __shared__ u16 smem[16384];
  const int tid = threadIdx.x;

  if ((int)blockIdx.x >= rec_blocks) {
    // ---------------- GEMM (BK=64 + both-sides swizzle) ----------------
    u16* As = smem;
    u16* Bs = smem + 8192;
    const int bk = blockIdx.x - rec_blocks;
    const int bn = bk & 31;
    const int bmo = bk >> 5;
    const int bm = (bmo & 1) ? (127 - (bmo >> 1)) : (bmo >> 1);   // ends-first
    const int lane = tid & 63;
    const int wv = tid >> 6;
    const int wm = wv >> 1, wn = wv & 1;
    const u16* Xb = X + (size_t)bm * 128 * 1024;
    const u16* Wb = W + (size_t)bn * 128 * 1024;
    const int srow_in = lane >> 3;
    const int sg      = (lane & 7) ^ srow_in;
    f32x4 acc[4][4] = {};
    for (int k0 = 0; k0 < 1024; k0 += 64) {
      #pragma unroll
      for (int n = 0; n < 4; ++n) {
        const int c = n * 4 + wv;
        const int r = c * 8 + srow_in;
        __builtin_amdgcn_global_load_lds(GPTR(Xb + (size_t)r * 1024 + k0 + sg * 8),
                                         LPTR(&As[c * 512 + lane * 8]), 16, 0, 0);
        __builtin_amdgcn_global_load_lds(GPTR(Wb + (size_t)r * 1024 + k0 + sg * 8),
                                         LPTR(&Bs[c * 512 + lane * 8]), 16, 0, 0);
      }
      __syncthreads();
      const int kq0 = lane >> 4;
      bf16x8 a4[4][2], b4[4][2];
      #pragma unroll
      for (int mt = 0; mt < 4; ++mt) {
        const int ra = wm * 64 + mt * 16 + (lane & 15);
        #pragma unroll
        for (int h = 0; h < 2; ++h)
          a4[mt][h] = *(const bf16x8*)&As[ra * 64 + (((kq0 + h * 4) ^ (ra & 7)) * 8)];
      }
      #pragma unroll
      for (int nt = 0; nt < 4; ++nt) {
        const int rb = wn * 64 + nt * 16 + (lane & 15);
        #pragma unroll
        for (int h = 0; h < 2; ++h)
          b4[nt][h] = *(const bf16x8*)&Bs[rb * 64 + (((kq0 + h * 4) ^ (rb & 7)) * 8)];
      }
      #pragma unroll
      for (int mt = 0; mt < 4; ++mt)
        #pragma unroll
        for (int nt = 0; nt < 4; ++nt) {
          acc[mt][nt] = __builtin_amdgcn_mfma_f32_16x16x32_bf16(a4[mt][0], b4[nt][0], acc[mt][nt], 0, 0, 0);
          acc[mt][nt] = __builtin_amdgcn_mfma_f32_16x16x32_bf16(a4[mt][1], b4[nt][1], acc[mt][nt], 0, 0, 0);
        }
      __syncthreads();
    }
    #pragma unroll
    for (int mt = 0; mt < 4; ++mt) {
      const int mbase = bm * 128 + wm * 64 + mt * 16 + ((lane >> 4) << 2);
      #pragma unroll
      for (int nt = 0; nt < 4; ++nt) {
        const int n = bn * 128 + wn * 64 + nt * 16 + (lane & 15);
        const float bi = bias[n];
        const int d = n >> 11;
        const int nn = n & 2047;
        const int q = nn >> 9;
        const int j = nn & 511;
        const int col = (j >> 4) * 64 + q * 16 + (j & 15);
        #pragma unroll
        for (int r = 0; r < 4; ++r) {
          const int mm = mbase + r;
          const int t = mm >> 5, b = mm & 31;
          gx[((size_t)(d * 512 + t) * 32 + b) * 2048 + col] = f2bf(acc[mt][nt][r] + bi);
        }
      }
    }
    return;
  }

  // ---------------- RECURRENCE ----------------
  float (*G)[32][68] = (float(*)[32][68])smem;
  const int bid = blockIdx.x;
  const int dir = bid >> 5;
  const int db = bid & 31;
  const int j0 = db * 16;
  const int lane = tid & 63;
  const int wv = tid >> 6;
  const int mh = wv >> 1, nh = wv & 1;
  const int R = lane & 15;
  const int ks = lane >> 4;

  bf16x8 bw[2][16];
  {
    #pragma unroll
    for (int nt = 0; nt < 2; ++nt) {
      const int q = nh * 2 + nt;
      const float* wp = whh + ((size_t)dir * 2048 + q * 512 + j0 + R) * 512 + ks * 8;
      #pragma unroll
      for (int kt = 0; kt < 16; ++kt) {
        float4 v0 = *(const float4*)(wp + kt * 32);
        float4 v1 = *(const float4*)(wp + kt * 32 + 4);
        union { u16 u[8]; bf16x8 v; } t;
        t.u[0] = f2bf(v0.x); t.u[1] = f2bf(v0.y); t.u[2] = f2bf(v0.z); t.u[3] = f2bf(v0.w);
        t.u[4] = f2bf(v1.x); t.u[5] = f2bf(v1.y); t.u[6] = f2bf(v1.z); t.u[7] = f2bf(v1.w);
        bw[nt][kt] = t.v;
      }
    }
  }

  const int eb = tid >> 3;
  const int pr = (tid & 7) * 2;
  float c0 = 0.f, c1 = 0.f;

  const size_t dirbase = (size_t)dir * 512 * 16384;
  const u16* apbase = hstep + dirbase + (size_t)(ks >> 1) * 512 + (mh * 16 + R) * 16 + (ks & 1) * 8;
  const u16* prbase = hstep + dirbase + (size_t)(lane & 31) * 512 + 510;
  const u16* gxeb   = gx + ((size_t)dir * 512 * 32 + eb) * 2048 + db * 64 + pr;

  uint32_t gq[4];
  {
    const int t0 = dir ? 511 : 0;
    const uint32_t* g0 = (const uint32_t*)(gxeb + (size_t)t0 * 65536);
    gq[0] = g0[0]; gq[1] = g0[8]; gq[2] = g0[16]; gq[3] = g0[24];
  }

  for (int s = 0; s < 512; ++s) {
    const int tcur = dir ? (511 - s) : s;
    const int gb = s & 1;
    f32x4 acc0 = {0.f,0.f,0.f,0.f}, acc1 = {0.f,0.f,0.f,0.f};

    if (s) {
      const size_t slot = (size_t)(s - 1) * 16384;
      const u16* ap = apbase + slot;
      __builtin_amdgcn_s_sleep(16);
      {
        const u16* pp = prbase + slot;
        while (true) {
          uint32_t fv;
          asm volatile("global_load_dword %0, %1, off sc0 sc1\n\ts_waitcnt vmcnt(0)"
                       : "=v"(fv) : "v"(pp) : "memory");
          if (__all((int)(fv != 0xFFFFFFFFu))) break;
        }
      }
      __builtin_amdgcn_sched_barrier(0);
      uint4 afu[16];
      #pragma unroll
      for (int kt = 0; kt < 16; ++kt)
        asm volatile("global_load_dwordx4 %0, %1, off sc0 sc1"
                     : "=v"(afu[kt]) : "v"(ap + kt * 1024) : "memory");
      asm volatile("s_waitcnt vmcnt(8)" ::: "memory");
      __builtin_amdgcn_sched_barrier(0);
      while (true) {
        unsigned mask = 0;
        #pragma unroll
        for (int kt = 0; kt < 8; ++kt) {
          int ok = (afu[kt].x != 0xFFFFFFFFu) && (afu[kt].y != 0xFFFFFFFFu) &&
                   (afu[kt].z != 0xFFFFFFFFu) && (afu[kt].w != 0xFFFFFFFFu);
          if (!__all(ok)) mask |= 1u << kt;
        }
        if (!mask) break;
        #pragma unroll
        for (int kt = 0; kt < 8; ++kt)
          if (mask & (1u << kt))
            asm volatile("global_load_dwordx4 %0, %1, off sc0 sc1"
                         : "=v"(afu[kt]) : "v"(ap + kt * 1024) : "memory");
        asm volatile("s_waitcnt vmcnt(0)" ::: "memory");
        __builtin_amdgcn_sched_barrier(0);
      }
      f32x4 a0 = {0.f,0.f,0.f,0.f}, a1 = {0.f,0.f,0.f,0.f};
      f32x4 b0 = {0.f,0.f,0.f,0.f}, b1 = {0.f,0.f,0.f,0.f};
      #pragma unroll
      for (int kt = 0; kt < 8; kt += 2) {
        bf16x8 x = __builtin_bit_cast(bf16x8, afu[kt]);
        bf16x8 y = __builtin_bit_cast(bf16x8, afu[kt + 1]);
        a0 = __builtin_amdgcn_mfma_f32_16x16x32_bf16(x, bw[0][kt],     a0, 0, 0, 0);
        a1 = __builtin_amdgcn_mfma_f32_16x16x32_bf16(x, bw[1][kt],     a1, 0, 0, 0);
        b0 = __builtin_amdgcn_mfma_f32_16x16x32_bf16(y, bw[0][kt + 1], b0, 0, 0, 0);
        b1 = __builtin_amdgcn_mfma_f32_16x16x32_bf16(y, bw[1][kt + 1], b1, 0, 0, 0);
      }
      asm volatile("s_waitcnt vmcnt(0)" ::: "memory");
      __builtin_amdgcn_sched_barrier(0);
      while (true) {
        unsigned mask = 0;
        #pragma unroll
        for (int kt = 8; kt < 16; ++kt) {
          int ok = (afu[kt].x != 0xFFFFFFFFu) && (afu[kt].y != 0xFFFFFFFFu) &&
                   (afu[kt].z != 0xFFFFFFFFu) && (afu[kt].w != 0xFFFFFFFFu);
          if (!__all(ok)) mask |= 1u << (kt - 8);
        }
        if (!mask) break;
        #pragma unroll
        for (int kt = 8; kt < 16; ++kt)
          if (mask & (1u << (kt - 8)))
            asm volatile("global_load_dwordx4 %0, %1, off sc0 sc1"
                         : "=v"(afu[kt]) : "v"(ap + kt * 1024) : "memory");
        asm volatile("s_waitcnt vmcnt(0)" ::: "memory");
        __builtin_amdgcn_sched_barrier(0);
      }
      #pragma unroll
      for (int kt = 8; kt < 16; kt += 2) {
        bf16x8 x = __builtin_bit_cast(bf16x8, afu[kt]);
        bf16x8 y = __builtin_bit_cast(bf16x8, afu[kt + 1]);
        a0 = __builtin_amdgcn_mfma_f32_16x16x32_bf16(x, bw[0][kt],     a0, 0, 0, 0);
        a1 = __builtin_amdgcn_mfma_f32_16x16x32_bf16(x, bw[1][kt],     a1, 0, 0, 0);
        b0 = __builtin_amdgcn_mfma_f32_16x16x32_bf16(y, bw[0][kt + 1], b0, 0, 0, 0);
        b1 = __builtin_amdgcn_mfma_f32_16x16x32_bf16(y, bw[1][kt + 1], b1, 0, 0, 0);
      }
      acc0 = a0 + b0;
      acc1 = a1 + b1;
    }

    #pragma unroll
    for (int r = 0; r < 4; ++r) {
      G[gb][mh * 16 + (lane >> 4) * 4 + r][nh * 32 + (lane & 15)]      = acc0[r];
      G[gb][mh * 16 + (lane >> 4) * 4 + r][nh * 32 + 16 + (lane & 15)] = acc1[r];
    }
    __syncthreads();

    {
      int ok = GVALID(gq[0]) & GVALID(gq[1]) & GVALID(gq[2]) & GVALID(gq[3]);
      if (!__all(ok)) {
        const u16* gp = gxeb + (size_t)tcur * 65536;
        while (true) {
          asm volatile("global_load_dword %0, %1, off sc0 sc1" : "=v"(gq[0]) : "v"(gp +  0) : "memory");
          asm volatile("global_load_dword %0, %1, off sc0 sc1" : "=v"(gq[1]) : "v"(gp + 16) : "memory");
          asm volatile("global_load_dword %0, %1, off sc0 sc1" : "=v"(gq[2]) : "v"(gp + 32) : "memory");
          asm volatile("global_load_dword %0, %1, off sc0 sc1" : "=v"(gq[3]) : "v"(gp + 48) : "memory");
          asm volatile("s_waitcnt vmcnt(0)" ::: "memory");
          __builtin_amdgcn_sched_barrier(0);
          ok = GVALID(gq[0]) & GVALID(gq[1]) & GVALID(gq[2]) & GVALID(gq[3]);
          if (__all(ok)) break;
        }
      }
    }

    {
      float i0 = G[gb][eb][pr]      + bf2f((u16)(gq[0] & 0xFFFF));
      float i1 = G[gb][eb][pr + 1]  + bf2f((u16)(gq[0] >> 16));
      float f0 = G[gb][eb][pr + 16] + bf2f((u16)(gq[1] & 0xFFFF));
      float f1 = G[gb][eb][pr + 17] + bf2f((u16)(gq[1] >> 16));
      float g0 = G[gb][eb][pr + 32] + bf2f((u16)(gq[2] & 0xFFFF));
      float g1 = G[gb][eb][pr + 33] + bf2f((u16)(gq[2] >> 16));
      float o0 = G[gb][eb][pr + 48] + bf2f((u16)(gq[3] & 0xFFFF));
      float o1 = G[gb][eb][pr + 49] + bf2f((u16)(gq[3] >> 16));
      c0 = sigf(f0) * c0 + sigf(i0) * tanhf_(g0);
      c1 = sigf(f1) * c1 + sigf(i1) * tanhf_(g1);
      float h0 = sigf(o0) * tanhf_(c0);
      float h1 = sigf(o1) * tanhf_(c1);
      uint32_t hp = (uint32_t)f2bf(h0) | ((uint32_t)f2bf(h1) << 16);
      u16* hdst = hstep + dirbase + (size_t)s * 16384 + (size_t)db * 512 + eb * 16 + pr;
      asm volatile("global_store_dword %0, %1, off sc0 sc1"
                   :: "v"(hdst), "v"(hp) : "memory");
      *(uint32_t*)(xout + ((size_t)tcur * 32 + eb) * 1024 + dir * 512 + j0 + pr) = hp;
    }
    if (s < 511) {
      const int tn = dir ? (511 - (s + 1)) : (s + 1);
      const uint32_t* gn = (const uint32_t*)(gxeb + (size_t)tn * 65536);
      gq[0] = gn[0]; gq[1] = gn[8]; gq[2] = gn[16]; gq[3] = gn[24];
    }
  }
}

// ---------------- classifier stage 1 (self-computes marker idx; x3 layout [t][b][1024]) ----------------
__global__ void k_cls1(const u16* __restrict__ x3, const int* __restrict__ seq,
                       const float* __restrict__ w1, const float* __restrict__ b1,
                       float* __restrict__ h1) {
  __shared__ u16 hid[32][1024];
  __shared__ int sidx[32];
  const int tid = threadIdx.x;
  {
    const int b = tid >> 3, part = tid & 7;
    for (int t = part * 64; t < part * 64 + 64; ++t)
      if (seq[b * 512 + t] == 50000) sidx[b] = t;
  }
  __syncthreads();
  for (int g = tid; g < 4096; g += 256) {
    const int b = g >> 7;
    const int c8 = (g & 127) * 8;
    *(uint4*)&hid[b][c8] = *(const uint4*)(x3 + ((size_t)sidx[b] * 32 + b) * 1024 + c8);
  }
  __syncthreads();
  for (int p = tid; p < 1024; p += 256) {
    const int j = blockIdx.x * 32 + (p >> 5);
    const int b = p & 31;
    const float4* wr = (const float4*)(w1 + (size_t)j * 1024);
    float s = 0.f;
    for (int k4 = 0; k4 < 256; ++k4) {
      float4 wv = wr[k4];
      const int k = k4 * 4;
      s += bf2f(hid[b][k]) * wv.x + bf2f(hid[b][k + 1]) * wv.y
         + bf2f(hid[b][k + 2]) * wv.z + bf2f(hid[b][k + 3]) * wv.w;
    }
    h1[b * 512 + j] = tanhf_(s + b1[j]);
  }
}

// ---------------- classifier stage 2: BCE-with-logits mean ----------------
__global__ void k_cls2(const float* __restrict__ h1, const float* __restrict__ w2,
                       const float* __restrict__ b2, const float* __restrict__ label,
                       float* __restrict__ out) {
  const int lane = threadIdx.x;   // 64
  float loss = 0.f;
  for (int b = 0; b < 32; ++b) {
    float s = 0.f;
    for (int k = lane; k < 512; k += 64) s += h1[b * 512 + k] * w2[k];
    for (int off = 32; off; off >>= 1) s += __shfl_down(s, off);
    if (lane == 0) {
      const float z = s + b2[0];
      const float y = label[b];
      const float sp = fmaxf(z, 0.f) + log1pf(__expf(-fabsf(z)));
      loss += sp - z * y;
    }
  }
  if (lane == 0) out[0] = loss / 32.0f;
}

extern "C" void kernel_launch(void* const* d_in, const int* in_sizes, int n_in,
                              void* d_out, int out_size, void* d_ws, size_t ws_size,
                              hipStream_t stream) {
  const int*   seq   = (const int*)  d_in[0];
  const float* label = (const float*)d_in[1];
  const float* wemb  = (const float*)d_in[2];
  const float* wih   = (const float*)d_in[3];
  const float* whh   = (const float*)d_in[4];
  const float* bb    = (const float*)d_in[5];
  const float* w1    = (const float*)d_in[6];
  const float* b1    = (const float*)d_in[7];
  const float* w2    = (const float*)d_in[8];
  const float* b2    = (const float*)d_in[9];

  // layout: gxb+hs contiguous (one 160MB memset), wb1+wb2 contiguous (one cast)
  u16* x1   = (u16*)d_ws;                       // [512][32][1024] bf16
  u16* x2   = x1 + (size_t)16777216;            // [512][32][1024] bf16
  u16* gxb  = x2 + (size_t)16777216;            // [2][512][32][2048] bf16 (128MB)
  u16* hs   = gxb + (size_t)67108864;           // [2][512][32][32][16] bf16 (32MB)
  u16* wb1  = hs + (size_t)16777216;            // [4096][1024] bf16
  u16* wb2  = wb1 + (size_t)4194304;            // [4096][1024] bf16
  float* h1 = (float*)(wb2 + 4194304);          // [32][512] f32
  const size_t need = (size_t)((char*)(h1 + 16384) - (char*)d_ws);
  const bool fused = ws_size >= need;

  k_emb<<<16384, 256, 0, stream>>>(seq, wemb, x1);

  if (fused) {
    k_cast<<<8192, 256, 0, stream>>>(wih, wb1);               // both layers (wb1|wb2 contiguous)
    // layer 1 (gemm ∥ rec)
    hipMemsetAsync(gxb, 0xFF, (size_t)167772160, stream);     // gx + hs in one shot
    k_fused<<<64 + 4096, 256, 0, stream>>>(64, x1, wb1, bb, gxb, whh, x2, hs);
    // layer 2 (gemm ∥ rec)
    hipMemsetAsync(gxb, 0xFF, (size_t)167772160, stream);
    k_fused<<<64 + 4096, 256, 0, stream>>>(64, x2, wb2, bb + 4096, gxb, whh + 2097152, x1, hs);
  } else {
    // serial fallback (hstep overlays dead X buffers)
    k_cast<<<4096, 256, 0, stream>>>(wih, wb1);
    k_fused<<<4096, 256, 0, stream>>>(0, x1, wb1, bb, gxb, whh, x2, x1);
    hipMemsetAsync(x1, 0xFF, (size_t)33554432, stream);
    k_fused<<<64, 256, 0, stream>>>(64, x1, wb1, bb, gxb, whh, x2, x1);
    k_cast<<<4096, 256, 0, stream>>>(wih + 4194304, wb1);
    k_fused<<<4096, 256, 0, stream>>>(0, x2, wb1, bb + 4096, gxb, whh + 2097152, x1, x2);
    hipMemsetAsync(x2, 0xFF, (size_t)33554432, stream);
    k_fused<<<64, 256, 0, stream>>>(64, x2, wb1, bb + 4096, gxb, whh + 2097152, x1, x2);
  }
  k_cls1<<<16, 256, 0, stream>>>(x1, seq, w1, b1, h1);
  k_cls2<<<1, 64, 0, stream>>>(h1, w2, b2, label, (float*)d_out);
}